// Round 4
// baseline (265.880 us; speedup 1.0000x reference)
//
#include <hip/hip_runtime.h>
#include <hip/hip_bf16.h>
#include <cstdint>

typedef unsigned short ushort_t;
typedef __attribute__((ext_vector_type(8))) short short8;
typedef __attribute__((ext_vector_type(4))) short short4v;
typedef __attribute__((ext_vector_type(4))) float floatx4;
typedef __attribute__((ext_vector_type(4))) unsigned int uintx4;
typedef __attribute__((ext_vector_type(4))) unsigned short ushort4_t;

#define H_   16
#define DKV_ 64
#define DM_  1024
#define B_   2
#define NQ_  2048
#define NK_  2048

// fp32 -> bf16 round-to-nearest-even
__device__ __forceinline__ unsigned short f2bf(float f) {
  union { float f; unsigned int u; } v; v.f = f;
  unsigned int u = v.u;
  return (unsigned short)((u + 0x7fffu + ((u >> 16) & 1u)) >> 16);
}

// Trans ops via compiler-visible intrinsics (NOT inline asm) — R5-proven.
__device__ __forceinline__ float fexp2(float x) { return __builtin_amdgcn_exp2f(x); }
__device__ __forceinline__ float frcp(float x)  { return __builtin_amdgcn_rcpf(x); }

// packed fp32x2 -> bf16x2 (RTNE). No builtin on gfx950; asm is T12-proven in attn.
__device__ __forceinline__ unsigned int cvt_pk_bf16(float lo, float hi) {
  unsigned int r;
  asm("v_cvt_pk_bf16_f32 %0, %1, %2" : "=v"(r) : "v"(lo), "v"(hi));
  return r;
}

__device__ __forceinline__ floatx4 mfma16(short8 a, short8 b, floatx4 c) {
  return __builtin_amdgcn_mfma_f32_16x16x32_bf16(a, b, c, 0, 0, 0);
}

// async global->LDS, 16B per lane; LDS dest = wave-uniform base + lane*16
__device__ __forceinline__ void gload_lds16(const ushort_t* g, ushort_t* l) {
  __builtin_amdgcn_global_load_lds(
      (const __attribute__((address_space(1))) void*)g,
      (__attribute__((address_space(3))) void*)l, 16, 0, 0);
}

// ---------------- cast kernels (R7-proven) --------------------------------
__global__ __launch_bounds__(256) void cast_x_kernel(
    const float* __restrict__ q, const float* __restrict__ k,
    const float* __restrict__ v, ushort_t* __restrict__ dst)
{
  const int t = blockIdx.y;
  const float* src = (t == 0) ? q : (t == 1) ? k : v;
  ushort_t* d = dst + (size_t)t * 4096 * 1024;
  const int gid = blockIdx.x * 256 + threadIdx.x;
  #pragma unroll
  for (int u = 0; u < 8; u++) {
    const int i4 = u * 131072 + gid;
    floatx4 f = ((const floatx4*)src)[i4];
    ushort4_t o;
    #pragma unroll
    for (int e = 0; e < 4; e++) o[e] = f2bf(f[e]);
    *(ushort4_t*)&d[(size_t)i4 * 4] = o;
  }
}

__global__ __launch_bounds__(256) void cast_wt_kernel(
    const float* __restrict__ Wq, const float* __restrict__ Wk,
    const float* __restrict__ Wv, ushort_t* __restrict__ WtAll)
{
  __shared__ ushort_t tile[32][33];
  const int t = blockIdx.z;
  const float* W = (t == 0) ? Wq : (t == 1) ? Wk : Wv;
  ushort_t* Wt = WtAll + (size_t)t * 1024 * 1024;
  const int n0 = blockIdx.x * 32, k0 = blockIdx.y * 32;
  const int tid = threadIdx.x, r = tid >> 3, c4 = (tid & 7) * 4;
  floatx4 f = *(const floatx4*)&W[(size_t)(k0 + r) * 1024 + n0 + c4];
  #pragma unroll
  for (int e = 0; e < 4; e++) tile[r][c4 + e] = f2bf(f[e]);
  __syncthreads();
  ushort4_t o;
  #pragma unroll
  for (int e = 0; e < 4; e++) o[e] = tile[c4 + e][r];
  *(ushort4_t*)&Wt[(size_t)(n0 + r) * 1024 + k0 + c4] = o;
}

// ---------------- proj v2 (R7-proven, byte-identical) ---------------------
__global__ __launch_bounds__(256, 2) void proj_kernel2(
    const ushort_t* __restrict__ Xbf, const ushort_t* __restrict__ WtAll,
    const float* __restrict__ bq, const float* __restrict__ bk,
    const float* __restrict__ bv,
    ushort_t* __restrict__ Qb, ushort_t* __restrict__ Kb, ushort_t* __restrict__ Vt)
{
  const int mode = blockIdx.z;
  const ushort_t* X  = Xbf  + (size_t)mode * 4096 * 1024;
  const ushort_t* Wt = WtAll + (size_t)mode * 1024 * 1024;
  const float* bias  = (mode == 0) ? bq : (mode == 1) ? bk : bv;
  ushort_t* dst      = (mode == 0) ? Qb : (mode == 1) ? Kb : Vt;

  __shared__ ushort_t SM[8192];
  ushort_t* SA = SM;
  ushort_t* SB = SM + 4096;

  const int tid = threadIdx.x, lane = tid & 63, wid = tid >> 6;
  const int c = lane & 15, g = lane >> 4;
  const int m0 = blockIdx.y * 128, n0 = blockIdx.x * 128;
  const int wm = wid & 1, wn = wid >> 1, mb = wm * 64, nb = wn * 64;
  const int srow = lane >> 2;
  const int schunk = (lane & 3) * 8;

  floatx4 acc[4][4];
  #pragma unroll
  for (int i = 0; i < 4; i++)
    #pragma unroll
    for (int j = 0; j < 4; j++) acc[i][j] = floatx4{0.f, 0.f, 0.f, 0.f};

  for (int k0 = 0; k0 < DM_; k0 += 32) {
    __syncthreads();
    #pragma unroll
    for (int u = 0; u < 2; u++) {
      const int t = wid * 2 + u;
      gload_lds16(&X [(size_t)(m0 + t * 16 + srow) * 1024 + k0 + schunk], &SA[t * 512]);
      gload_lds16(&Wt[(size_t)(n0 + t * 16 + srow) * 1024 + k0 + schunk], &SB[t * 512]);
    }
    __syncthreads();

    short8 af[4], bfr[4];
    #pragma unroll
    for (int i = 0; i < 4; i++) af[i]  = *(const short8*)&SA[(mb + i * 16 + c) * 32 + g * 8];
    #pragma unroll
    for (int j = 0; j < 4; j++) bfr[j] = *(const short8*)&SB[(nb + j * 16 + c) * 32 + g * 8];
    #pragma unroll
    for (int i = 0; i < 4; i++)
      #pragma unroll
      for (int j = 0; j < 4; j++) acc[i][j] = mfma16(af[i], bfr[j], acc[i][j]);
  }

  __syncthreads();
  const float scale = (mode == 0) ? 0.18033688011112042f : 1.0f;
  ushort_t* EP = SM + wid * 2048;
  const int hh = (n0 + nb) >> 6;

  if (mode != 2) {
    for (int jj = 0; jj < 2; jj++) {
      #pragma unroll
      for (int jt = 0; jt < 2; jt++) {
        const int j = jj * 2 + jt;
        const float bb = bias[n0 + nb + j * 16 + c];
        #pragma unroll
        for (int i = 0; i < 4; i++)
          #pragma unroll
          for (int r = 0; r < 4; r++)
            EP[(i * 16 + g * 4 + r) * 32 + jt * 16 + c] =
                f2bf((acc[i][j][r] + bb) * scale);
      }
      #pragma unroll
      for (int u = 0; u < 8; u++) {
        const int rowl = u * 8 + (lane >> 3);
        ushort4_t vv = *(ushort4_t*)&EP[rowl * 32 + (lane & 7) * 4];
        const int rowg = m0 + mb + rowl;
        const int bb2 = rowg >> 11, nn = rowg & 2047;
        *(ushort4_t*)&dst[((size_t)(bb2 * H_ + hh) * NQ_ + nn) * DKV_ +
                          jj * 32 + (lane & 7) * 4] = vv;
      }
    }
  } else {
    const int bb2 = (m0 + mb) >> 11, nloc = (m0 + mb) & 2047;
    for (int j = 0; j < 4; j++) {
      const float bb = bias[n0 + nb + j * 16 + c];
      #pragma unroll
      for (int i = 0; i < 4; i++) {
        ushort4_t pk;
        #pragma unroll
        for (int r = 0; r < 4; r++) pk[r] = f2bf(acc[i][j][r] + bb);
        *(ushort4_t*)&EP[c * 72 + i * 16 + g * 4] = pk;
      }
      const int d0 = j * 16;
      #pragma unroll
      for (int u = 0; u < 2; u++) {
        const int coll = u * 8 + (lane >> 3);
        short8 vv = *(const short8*)&EP[coll * 72 + (lane & 7) * 8];
        *(short8*)&dst[((size_t)(bb2 * H_ + hh) * DKV_ + d0 + coll) * NK_ +
                       nloc + (lane & 7) * 8] = vv;
      }
    }
  }
}

// ---------------- proj fallback (R2/R5-proven) ----------------------------
constexpr int LDT = 40;
__global__ __launch_bounds__(256, 2) void proj_kernel_fb(
    const float* __restrict__ Xq, const float* __restrict__ Xk, const float* __restrict__ Xv,
    const float* __restrict__ Wq, const float* __restrict__ Wk, const float* __restrict__ Wv,
    const float* __restrict__ bq, const float* __restrict__ bk, const float* __restrict__ bv,
    ushort_t* __restrict__ Qb, ushort_t* __restrict__ Kb, ushort_t* __restrict__ Vt)
{
  const int mode = blockIdx.z;
  const float* X    = (mode == 0) ? Xq : (mode == 1) ? Xk : Xv;
  const float* W    = (mode == 0) ? Wq : (mode == 1) ? Wk : Wv;
  const float* bias = (mode == 0) ? bq : (mode == 1) ? bk : bv;
  ushort_t* dst     = (mode == 0) ? Qb : (mode == 1) ? Kb : Vt;

  __shared__ ushort_t Asm[128 * LDT];
  __shared__ ushort_t Bsm[128 * LDT];

  const int tid = threadIdx.x, lane = tid & 63, wid = tid >> 6;
  const int m0 = blockIdx.y * 128, n0 = blockIdx.x * 128;
  const int c = lane & 15, g = lane >> 4;
  const int wm = wid & 1, wn = wid >> 1, mb = wm * 64, nb = wn * 64;

  floatx4 acc[4][4];
  #pragma unroll
  for (int i = 0; i < 4; i++)
    #pragma unroll
    for (int j = 0; j < 4; j++) acc[i][j] = floatx4{0.f, 0.f, 0.f, 0.f};

  const int ar = tid >> 1, ah = tid & 1;
  const int bn = tid & 127, bh2 = tid >> 7;

  for (int k0 = 0; k0 < DM_; k0 += 32) {
    const floatx4* ap = (const floatx4*)(X + (size_t)(m0 + ar) * DM_ + k0 + ah * 16);
    floatx4 av0 = ap[0], av1 = ap[1], av2 = ap[2], av3 = ap[3];
    const float* wp = W + (size_t)(k0 + bh2 * 16) * 1024 + n0 + bn;
    float wv[16];
    #pragma unroll
    for (int j = 0; j < 16; j++) wv[j] = wp[j * 1024];
    short8 pa0, pa1, pb0, pb1;
    #pragma unroll
    for (int j = 0; j < 4; j++) {
      pa0[j] = (short)f2bf(av0[j]); pa0[4 + j] = (short)f2bf(av1[j]);
      pa1[j] = (short)f2bf(av2[j]); pa1[4 + j] = (short)f2bf(av3[j]);
    }
    #pragma unroll
    for (int j = 0; j < 8; j++) { pb0[j] = (short)f2bf(wv[j]); pb1[j] = (short)f2bf(wv[8 + j]); }
    __syncthreads();
    *(short8*)&Asm[ar * LDT + ah * 16]      = pa0;
    *(short8*)&Asm[ar * LDT + ah * 16 + 8]  = pa1;
    *(short8*)&Bsm[bn * LDT + bh2 * 16]     = pb0;
    *(short8*)&Bsm[bn * LDT + bh2 * 16 + 8] = pb1;
    __syncthreads();
    short8 af[4], bfr[4];
    #pragma unroll
    for (int i = 0; i < 4; i++) af[i]  = *(const short8*)&Asm[(mb + i * 16 + c) * LDT + g * 8];
    #pragma unroll
    for (int j = 0; j < 4; j++) bfr[j] = *(const short8*)&Bsm[(nb + j * 16 + c) * LDT + g * 8];
    #pragma unroll
    for (int i = 0; i < 4; i++)
      #pragma unroll
      for (int j = 0; j < 4; j++) acc[i][j] = mfma16(af[i], bfr[j], acc[i][j]);
  }
  #pragma unroll
  for (int j = 0; j < 4; j++) {
    const int col = n0 + nb + j * 16 + c;
    const float bv_ = bias[col];
    const int h = col >> 6, d = col & 63;
    #pragma unroll
    for (int i = 0; i < 4; i++)
      #pragma unroll
      for (int r = 0; r < 4; r++) {
        const int row = m0 + mb + i * 16 + g * 4 + r;
        const int b = row >> 11, n = row & 2047;
        float v = acc[i][j][r] + bv_;
        if (mode == 0) {
          v *= 0.18033688011112042f;
          dst[((size_t)(b * H_ + h) * NQ_ + n) * DKV_ + d] = f2bf(v);
        } else if (mode == 1) {
          dst[((size_t)(b * H_ + h) * NQ_ + n) * DKV_ + d] = f2bf(v);
        } else {
          dst[((size_t)(b * H_ + h) * DKV_ + d) * NK_ + n] = f2bf(v);
        }
      }
  }
}

// ---------------- attn v8: in-block split-k, 32 waves/CU ------------------
// R3 post-mortem: three schedule restructures all neutral => limiter is TLP
// (grid-capped at 2 blocks/CU = 4 waves/SIMD, all pipes <40%).
// v8: 8 waves = 4 q-subtiles x 2 k-halves (waves 0-3: k<1024, 4-7: k>=1024),
// 64 q/block => grid (16,32,2) = 1024 blocks = exactly 4 blocks/CU,
// 32 waves/CU = 8 waves/SIMD. Requirements met by: KVBLK=32, K via
// global_load_lds into UNPADDED [32][64] with XOR-swizzle pair
// (src chunk (lane&7)^((lane>>3)&7), read granule ((kc*4+g)^(c&7)) — 2-way
// = free), V reg-staged with sigma permute (8B granular), both dbuf:
// LDS 36.9KB/block (147.5/CU), no cross-iteration regs => VGPR<=64
// (__launch_bounds__(512,8) enforces; THE critical resource).
// Split-k merge: softmax has no running max => partials add exactly;
// group1 passes (o,l) via LDS once at the end, group0 normalizes+stores.
__global__ __launch_bounds__(512, 8) void attn_kernel(
    const ushort_t* __restrict__ Qb, const ushort_t* __restrict__ Kb,
    const ushort_t* __restrict__ Vt, const float* __restrict__ gp,
    float* __restrict__ out)
{
  // per group: K dbuf [2][32*64] (4096 sh) + V dbuf [2][64*40] (5120 sh)
  __shared__ ushort_t SMEM[2][9216];               // 36864 B total

  constexpr int NT = 32;                           // 1024 k / 32 per group

  const int tid = threadIdx.x, lane = tid & 63;
  const int wid = tid >> 6;                        // 0..7
  const int grp = wid >> 2;                        // k-half
  const int wid4 = wid & 3;                        // q-subtile
  const int c = lane & 15, g = lane >> 4;
  const int h = blockIdx.x, b = blockIdx.z;        // h fastest: gp L2 locality
  const int bh = b * H_ + h;
  const int qw = blockIdx.y * 64 + wid4 * 16;
  const int kbase = grp << 10;

  const ushort_t* Qp = Qb + (size_t)bh * NQ_ * DKV_;
  const ushort_t* Kp = Kb + (size_t)bh * NK_ * DKV_;
  const ushort_t* Vp = Vt + (size_t)bh * DKV_ * NK_;
  const float* gpq = gp + (size_t)b * NQ_ * NK_ + (size_t)(qw + c) * NK_;

  ushort_t* KsG = &SMEM[grp][0];                   // [2][32][64] shorts
  ushort_t* VsG = &SMEM[grp][4096];                // [2][64][40] shorts

  // V staging role (256 threads per group): 1 x 16B chunk each
  const int tid2 = tid & 255;
  const int srow = tid2 >> 2;                      // V d-row 0..63
  const int u    = tid2 & 3;                       // 16B chunk (k 8u..8u+8)
  const int so_lo = 8 * ((2 * u) & 3) + 4 * ((u >> 1) & 1);
  const int so_hi = 8 * ((2 * u + 1) & 3) + 4 * ((u >> 1) & 1);
  // K gload per-lane source (XOR-swizzled chunk within the row's 128B)
  const int krow = wid4 * 8 + (lane >> 3);         // row in 32-tile
  const int kscg = (lane & 7) ^ ((lane >> 3) & 7); // source 16B-chunk idx
  // K read: swizzled col granule (shorts) per kc
  const int kcol0 = ((0 + g) ^ (c & 7)) << 3;
  const int kcol1 = ((4 + g) ^ (c & 7)) << 3;

  // Q fragments resident (pre-scaled by log2(e)/8)
  const short8 qf0 = *(const short8*)&Qp[(qw + c) * DKV_ + g * 8];
  const short8 qf1 = *(const short8*)&Qp[(qw + c) * DKV_ + 32 + g * 8];

  // ---- stage tile 0 ----
  gload_lds16(&Kp[(size_t)(kbase + krow) * DKV_ + kscg * 8], &KsG[wid4 * 512]);
  {
    short8 v8 = *(const short8*)&Vp[(size_t)srow * NK_ + kbase + u * 8];
    short4v vl, vh;
    #pragma unroll
    for (int e = 0; e < 4; e++) { vl[e] = v8[e]; vh[e] = v8[4 + e]; }
    *(short4v*)&VsG[srow * 40 + so_lo] = vl;
    *(short4v*)&VsG[srow * 40 + so_hi] = vh;
  }
  __syncthreads();

  floatx4 o[4];
  float l = 0.f;
  #pragma unroll
  for (int jd = 0; jd < 4; jd++) o[jd] = floatx4{0.f, 0.f, 0.f, 0.f};

  for (int t = 0; t < NT; ++t) {
    const int cur = t & 1, nxt = cur ^ 1;
    const int k0 = kbase + t * 32;
    const bool hn = (t + 1) < NT;

    // prefetch tile t+1: K direct to LDS[nxt] (overlaps reads of [cur]),
    // V to regs (committed at end of body)
    if (hn)
      gload_lds16(&Kp[(size_t)(k0 + 32 + krow) * DKV_ + kscg * 8],
                  &KsG[nxt * 2048 + wid4 * 512]);
    short8 vr = {};
    if (hn) vr = *(const short8*)&Vp[(size_t)srow * NK_ + k0 + 32 + u * 8];

    // gp for current tile (row q=c, cols k0 + jk*16 + 4g..+4)
    const floatx4 gp0 = *(const floatx4*)&gpq[k0 + g * 4];
    const floatx4 gp1 = *(const floatx4*)&gpq[k0 + 16 + g * 4];

    // S = K Q^T (log2 domain): lane holds q=c, k = jk*16 + 4g + r
    const ushort_t* Kc = &KsG[cur * 2048];
    const ushort_t* Vc = &VsG[cur * 2560];
    floatx4 s0 = floatx4{0.f, 0.f, 0.f, 0.f};
    floatx4 s1 = floatx4{0.f, 0.f, 0.f, 0.f};
    s0 = mfma16(*(const short8*)&Kc[(c) * 64 + kcol0], qf0, s0);
    s0 = mfma16(*(const short8*)&Kc[(c) * 64 + kcol1], qf1, s0);
    s1 = mfma16(*(const short8*)&Kc[(16 + c) * 64 + kcol0], qf0, s1);
    s1 = mfma16(*(const short8*)&Kc[(16 + c) * 64 + kcol1], qf1, s1);

    // p = exp2(s); l += p; gate; pack A-frag in-register
    const float p00 = fexp2(s0[0]), p01 = fexp2(s0[1]);
    const float p02 = fexp2(s0[2]), p03 = fexp2(s0[3]);
    const float p10 = fexp2(s1[0]), p11 = fexp2(s1[1]);
    const float p12 = fexp2(s1[2]), p13 = fexp2(s1[3]);
    l += ((p00 + p01) + (p02 + p03)) + ((p10 + p11) + (p12 + p13));
    const unsigned int w0 = cvt_pk_bf16(p00 * gp0[0], p01 * gp0[1]);
    const unsigned int w1 = cvt_pk_bf16(p02 * gp0[2], p03 * gp0[3]);
    const unsigned int w2 = cvt_pk_bf16(p10 * gp1[0], p11 * gp1[1]);
    const unsigned int w3 = cvt_pk_bf16(p12 * gp1[2], p13 * gp1[3]);
    const uintx4 aw = uintx4{w0, w1, w2, w3};
    const short8 af = __builtin_bit_cast(short8, aw);

    // PV: A = in-register P frag, B = sigma-permuted V from LDS
    #pragma unroll
    for (int jd = 0; jd < 4; jd++) {
      short8 vf = *(const short8*)&Vc[(jd * 16 + c) * 40 + g * 8];
      o[jd] = mfma16(af, vf, o[jd]);
    }

    // commit V(t+1)
    if (hn) {
      short4v vl, vh;
      #pragma unroll
      for (int e = 0; e < 4; e++) { vl[e] = vr[e]; vh[e] = vr[4 + e]; }
      *(short4v*)&VsG[nxt * 2560 + srow * 40 + so_lo] = vl;
      *(short4v*)&VsG[nxt * 2560 + srow * 40 + so_hi] = vh;
    }
    __syncthreads();   // converge; drains K gload (vmcnt) + V commit (lgkm)
  }

  // ---- split-k merge: group1 -> LDS, group0 adds, normalizes, stores ----
  // (last loop iter ended with __syncthreads: K/V LDS dead, safe to reuse)
  float* M = (float*)&SMEM[0][0];                  // [4][64][17] f32 = 17408B
  if (grp == 1) {
    const int mi = (wid4 * 64 + lane) * 17;
    #pragma unroll
    for (int jd = 0; jd < 4; jd++) *(floatx4*)&M[mi + jd * 4] = o[jd];
    M[mi + 16] = l;
  }
  __syncthreads();
  if (grp == 0) {
    const int mi = (wid4 * 64 + lane) * 17;
    #pragma unroll
    for (int jd = 0; jd < 4; jd++) o[jd] += *(const floatx4*)&M[mi + jd * 4];
    l += M[mi + 16];

    float lf = l;
    lf += __shfl_xor(lf, 16);
    lf += __shfl_xor(lf, 32);
    const float inv = frcp(lf);
    float invr[4];
    #pragma unroll
    for (int r = 0; r < 4; r++) invr[r] = __shfl(inv, g * 4 + r);

    #pragma unroll
    for (int jd = 0; jd < 4; jd++)
      #pragma unroll
      for (int r = 0; r < 4; r++) {
        const int row = qw + g * 4 + r;
        out[(size_t)(b * NQ_ + row) * 1024 + h * 64 + jd * 16 + c] =
            o[jd][r] * invr[r];
      }
  }
}

extern "C" void kernel_launch(void* const* d_in, const int* in_sizes, int n_in,
                              void* d_out, int out_size, void* d_ws, size_t ws_size,
                              hipStream_t stream) {
  const float* queries = (const float*)d_in[0];
  const float* keys    = (const float*)d_in[1];
  const float* values  = (const float*)d_in[2];
  const float* gp      = (const float*)d_in[3];
  // d_in[4] attention_mask: intentionally unused (reference discards it)
  const float* Wq = (const float*)d_in[5];
  const float* bq = (const float*)d_in[6];
  const float* Wk = (const float*)d_in[7];
  const float* bk = (const float*)d_in[8];
  const float* Wv = (const float*)d_in[9];
  const float* bv = (const float*)d_in[10];

  const size_t SZ_QKV = (size_t)3 * B_ * H_ * NQ_ * DKV_;  // shorts
  const size_t SZ_X   = (size_t)3 * 4096 * 1024;
  const size_t SZ_W   = (size_t)3 * 1024 * 1024;
  const size_t NEED   = (SZ_QKV + SZ_X + SZ_W) * sizeof(ushort_t);

  ushort_t* Qb = (ushort_t*)d_ws;                       // [B,H,NQ,64] bf16, pre-scaled
  ushort_t* Kb = Qb + (size_t)B_ * H_ * NQ_ * DKV_;     // [B,H,NK,64] bf16
  ushort_t* Vt = Kb + (size_t)B_ * H_ * NK_ * DKV_;     // [B,H,64,NK] bf16
  float* out = (float*)d_out;

  if (ws_size >= NEED) {
    ushort_t* Xbf = Qb + SZ_QKV;
    ushort_t* Wt  = Xbf + SZ_X;
    cast_x_kernel<<<dim3(512, 3), 256, 0, stream>>>(queries, keys, values, Xbf);
    cast_wt_kernel<<<dim3(32, 32, 3), 256, 0, stream>>>(Wq, Wk, Wv, Wt);
    proj_kernel2<<<dim3(8, 32, 3), 256, 0, stream>>>(
        Xbf, Wt, bq, bk, bv, Qb, Kb, Vt);
  } else {
    proj_kernel_fb<<<dim3(8, 32, 3), 256, 0, stream>>>(
        queries, keys, values, Wq, Wk, Wv, bq, bk, bv, Qb, Kb, Vt);
  }
  attn_kernel<<<dim3(H_, NQ_ / 64, B_), 512, 0, stream>>>(Qb, Kb, Vt, gp, out);
}

// Round 5
// 251.924 us; speedup vs baseline: 1.0554x; 1.0554x over previous
//
#include <hip/hip_runtime.h>
#include <hip/hip_bf16.h>
#include <cstdint>

typedef unsigned short ushort_t;
typedef __attribute__((ext_vector_type(8))) short short8;
typedef __attribute__((ext_vector_type(4))) short short4v;
typedef __attribute__((ext_vector_type(4))) float floatx4;
typedef __attribute__((ext_vector_type(4))) unsigned int uintx4;
typedef __attribute__((ext_vector_type(4))) unsigned short ushort4_t;

#define H_   16
#define DKV_ 64
#define DM_  1024
#define B_   2
#define NQ_  2048
#define NK_  2048

// fp32 -> bf16 round-to-nearest-even
__device__ __forceinline__ unsigned short f2bf(float f) {
  union { float f; unsigned int u; } v; v.f = f;
  unsigned int u = v.u;
  return (unsigned short)((u + 0x7fffu + ((u >> 16) & 1u)) >> 16);
}

// Trans ops via compiler-visible intrinsics (NOT inline asm) — R5-proven.
__device__ __forceinline__ float fexp2(float x) { return __builtin_amdgcn_exp2f(x); }
__device__ __forceinline__ float frcp(float x)  { return __builtin_amdgcn_rcpf(x); }

// packed fp32x2 -> bf16x2 (RTNE). No builtin on gfx950; asm is T12-proven in attn.
__device__ __forceinline__ unsigned int cvt_pk_bf16(float lo, float hi) {
  unsigned int r;
  asm("v_cvt_pk_bf16_f32 %0, %1, %2" : "=v"(r) : "v"(lo), "v"(hi));
  return r;
}

__device__ __forceinline__ floatx4 mfma16(short8 a, short8 b, floatx4 c) {
  return __builtin_amdgcn_mfma_f32_16x16x32_bf16(a, b, c, 0, 0, 0);
}

// async global->LDS, 16B per lane; LDS dest = wave-uniform base + lane*16
__device__ __forceinline__ void gload_lds16(const ushort_t* g, ushort_t* l) {
  __builtin_amdgcn_global_load_lds(
      (const __attribute__((address_space(1))) void*)g,
      (__attribute__((address_space(3))) void*)l, 16, 0, 0);
}

// T4 barrier: drain LDS ops only (NOT vmem) before s_barrier, so prefetch
// global loads stay in flight across iterations.
__device__ __forceinline__ void block_sync_lds() {
  asm volatile("s_waitcnt lgkmcnt(0)" ::: "memory");
  __builtin_amdgcn_s_barrier();
  __builtin_amdgcn_sched_barrier(0);
}

// ---------------- cast kernels (R7-proven) --------------------------------
__global__ __launch_bounds__(256) void cast_x_kernel(
    const float* __restrict__ q, const float* __restrict__ k,
    const float* __restrict__ v, ushort_t* __restrict__ dst)
{
  const int t = blockIdx.y;
  const float* src = (t == 0) ? q : (t == 1) ? k : v;
  ushort_t* d = dst + (size_t)t * 4096 * 1024;
  const int gid = blockIdx.x * 256 + threadIdx.x;
  #pragma unroll
  for (int u = 0; u < 8; u++) {
    const int i4 = u * 131072 + gid;
    floatx4 f = ((const floatx4*)src)[i4];
    ushort4_t o;
    #pragma unroll
    for (int e = 0; e < 4; e++) o[e] = f2bf(f[e]);
    *(ushort4_t*)&d[(size_t)i4 * 4] = o;
  }
}

__global__ __launch_bounds__(256) void cast_wt_kernel(
    const float* __restrict__ Wq, const float* __restrict__ Wk,
    const float* __restrict__ Wv, ushort_t* __restrict__ WtAll)
{
  __shared__ ushort_t tile[32][33];
  const int t = blockIdx.z;
  const float* W = (t == 0) ? Wq : (t == 1) ? Wk : Wv;
  ushort_t* Wt = WtAll + (size_t)t * 1024 * 1024;
  const int n0 = blockIdx.x * 32, k0 = blockIdx.y * 32;
  const int tid = threadIdx.x, r = tid >> 3, c4 = (tid & 7) * 4;
  floatx4 f = *(const floatx4*)&W[(size_t)(k0 + r) * 1024 + n0 + c4];
  #pragma unroll
  for (int e = 0; e < 4; e++) tile[r][c4 + e] = f2bf(f[e]);
  __syncthreads();
  ushort4_t o;
  #pragma unroll
  for (int e = 0; e < 4; e++) o[e] = tile[c4 + e][r];
  *(ushort4_t*)&Wt[(size_t)(n0 + r) * 1024 + k0 + c4] = o;
}

// ---------------- proj v2 (R7-proven, byte-identical) ---------------------
__global__ __launch_bounds__(256, 2) void proj_kernel2(
    const ushort_t* __restrict__ Xbf, const ushort_t* __restrict__ WtAll,
    const float* __restrict__ bq, const float* __restrict__ bk,
    const float* __restrict__ bv,
    ushort_t* __restrict__ Qb, ushort_t* __restrict__ Kb, ushort_t* __restrict__ Vt)
{
  const int mode = blockIdx.z;
  const ushort_t* X  = Xbf  + (size_t)mode * 4096 * 1024;
  const ushort_t* Wt = WtAll + (size_t)mode * 1024 * 1024;
  const float* bias  = (mode == 0) ? bq : (mode == 1) ? bk : bv;
  ushort_t* dst      = (mode == 0) ? Qb : (mode == 1) ? Kb : Vt;

  __shared__ ushort_t SM[8192];
  ushort_t* SA = SM;
  ushort_t* SB = SM + 4096;

  const int tid = threadIdx.x, lane = tid & 63, wid = tid >> 6;
  const int c = lane & 15, g = lane >> 4;
  const int m0 = blockIdx.y * 128, n0 = blockIdx.x * 128;
  const int wm = wid & 1, wn = wid >> 1, mb = wm * 64, nb = wn * 64;
  const int srow = lane >> 2;
  const int schunk = (lane & 3) * 8;

  floatx4 acc[4][4];
  #pragma unroll
  for (int i = 0; i < 4; i++)
    #pragma unroll
    for (int j = 0; j < 4; j++) acc[i][j] = floatx4{0.f, 0.f, 0.f, 0.f};

  for (int k0 = 0; k0 < DM_; k0 += 32) {
    __syncthreads();
    #pragma unroll
    for (int u = 0; u < 2; u++) {
      const int t = wid * 2 + u;
      gload_lds16(&X [(size_t)(m0 + t * 16 + srow) * 1024 + k0 + schunk], &SA[t * 512]);
      gload_lds16(&Wt[(size_t)(n0 + t * 16 + srow) * 1024 + k0 + schunk], &SB[t * 512]);
    }
    __syncthreads();

    short8 af[4], bfr[4];
    #pragma unroll
    for (int i = 0; i < 4; i++) af[i]  = *(const short8*)&SA[(mb + i * 16 + c) * 32 + g * 8];
    #pragma unroll
    for (int j = 0; j < 4; j++) bfr[j] = *(const short8*)&SB[(nb + j * 16 + c) * 32 + g * 8];
    #pragma unroll
    for (int i = 0; i < 4; i++)
      #pragma unroll
      for (int j = 0; j < 4; j++) acc[i][j] = mfma16(af[i], bfr[j], acc[i][j]);
  }

  __syncthreads();
  const float scale = (mode == 0) ? 0.18033688011112042f : 1.0f;
  ushort_t* EP = SM + wid * 2048;
  const int hh = (n0 + nb) >> 6;

  if (mode != 2) {
    for (int jj = 0; jj < 2; jj++) {
      #pragma unroll
      for (int jt = 0; jt < 2; jt++) {
        const int j = jj * 2 + jt;
        const float bb = bias[n0 + nb + j * 16 + c];
        #pragma unroll
        for (int i = 0; i < 4; i++)
          #pragma unroll
          for (int r = 0; r < 4; r++)
            EP[(i * 16 + g * 4 + r) * 32 + jt * 16 + c] =
                f2bf((acc[i][j][r] + bb) * scale);
      }
      #pragma unroll
      for (int u = 0; u < 8; u++) {
        const int rowl = u * 8 + (lane >> 3);
        ushort4_t vv = *(ushort4_t*)&EP[rowl * 32 + (lane & 7) * 4];
        const int rowg = m0 + mb + rowl;
        const int bb2 = rowg >> 11, nn = rowg & 2047;
        *(ushort4_t*)&dst[((size_t)(bb2 * H_ + hh) * NQ_ + nn) * DKV_ +
                          jj * 32 + (lane & 7) * 4] = vv;
      }
    }
  } else {
    const int bb2 = (m0 + mb) >> 11, nloc = (m0 + mb) & 2047;
    for (int j = 0; j < 4; j++) {
      const float bb = bias[n0 + nb + j * 16 + c];
      #pragma unroll
      for (int i = 0; i < 4; i++) {
        ushort4_t pk;
        #pragma unroll
        for (int r = 0; r < 4; r++) pk[r] = f2bf(acc[i][j][r] + bb);
        *(ushort4_t*)&EP[c * 72 + i * 16 + g * 4] = pk;
      }
      const int d0 = j * 16;
      #pragma unroll
      for (int u = 0; u < 2; u++) {
        const int coll = u * 8 + (lane >> 3);
        short8 vv = *(const short8*)&EP[coll * 72 + (lane & 7) * 8];
        *(short8*)&dst[((size_t)(bb2 * H_ + hh) * DKV_ + d0 + coll) * NK_ +
                       nloc + (lane & 7) * 8] = vv;
      }
    }
  }
}

// ---------------- proj fallback (R2/R5-proven) ----------------------------
constexpr int LDT = 40;
__global__ __launch_bounds__(256, 2) void proj_kernel_fb(
    const float* __restrict__ Xq, const float* __restrict__ Xk, const float* __restrict__ Xv,
    const float* __restrict__ Wq, const float* __restrict__ Wk, const float* __restrict__ Wv,
    const float* __restrict__ bq, const float* __restrict__ bk, const float* __restrict__ bv,
    ushort_t* __restrict__ Qb, ushort_t* __restrict__ Kb, ushort_t* __restrict__ Vt)
{
  const int mode = blockIdx.z;
  const float* X    = (mode == 0) ? Xq : (mode == 1) ? Xk : Xv;
  const float* W    = (mode == 0) ? Wq : (mode == 1) ? Wk : Wv;
  const float* bias = (mode == 0) ? bq : (mode == 1) ? bk : bv;
  ushort_t* dst     = (mode == 0) ? Qb : (mode == 1) ? Kb : Vt;

  __shared__ ushort_t Asm[128 * LDT];
  __shared__ ushort_t Bsm[128 * LDT];

  const int tid = threadIdx.x, lane = tid & 63, wid = tid >> 6;
  const int m0 = blockIdx.y * 128, n0 = blockIdx.x * 128;
  const int c = lane & 15, g = lane >> 4;
  const int wm = wid & 1, wn = wid >> 1, mb = wm * 64, nb = wn * 64;

  floatx4 acc[4][4];
  #pragma unroll
  for (int i = 0; i < 4; i++)
    #pragma unroll
    for (int j = 0; j < 4; j++) acc[i][j] = floatx4{0.f, 0.f, 0.f, 0.f};

  const int ar = tid >> 1, ah = tid & 1;
  const int bn = tid & 127, bh2 = tid >> 7;

  for (int k0 = 0; k0 < DM_; k0 += 32) {
    const floatx4* ap = (const floatx4*)(X + (size_t)(m0 + ar) * DM_ + k0 + ah * 16);
    floatx4 av0 = ap[0], av1 = ap[1], av2 = ap[2], av3 = ap[3];
    const float* wp = W + (size_t)(k0 + bh2 * 16) * 1024 + n0 + bn;
    float wv[16];
    #pragma unroll
    for (int j = 0; j < 16; j++) wv[j] = wp[j * 1024];
    short8 pa0, pa1, pb0, pb1;
    #pragma unroll
    for (int j = 0; j < 4; j++) {
      pa0[j] = (short)f2bf(av0[j]); pa0[4 + j] = (short)f2bf(av1[j]);
      pa1[j] = (short)f2bf(av2[j]); pa1[4 + j] = (short)f2bf(av3[j]);
    }
    #pragma unroll
    for (int j = 0; j < 8; j++) { pb0[j] = (short)f2bf(wv[j]); pb1[j] = (short)f2bf(wv[8 + j]); }
    __syncthreads();
    *(short8*)&Asm[ar * LDT + ah * 16]      = pa0;
    *(short8*)&Asm[ar * LDT + ah * 16 + 8]  = pa1;
    *(short8*)&Bsm[bn * LDT + bh2 * 16]     = pb0;
    *(short8*)&Bsm[bn * LDT + bh2 * 16 + 8] = pb1;
    __syncthreads();
    short8 af[4], bfr[4];
    #pragma unroll
    for (int i = 0; i < 4; i++) af[i]  = *(const short8*)&Asm[(mb + i * 16 + c) * LDT + g * 8];
    #pragma unroll
    for (int j = 0; j < 4; j++) bfr[j] = *(const short8*)&Bsm[(nb + j * 16 + c) * LDT + g * 8];
    #pragma unroll
    for (int i = 0; i < 4; i++)
      #pragma unroll
      for (int j = 0; j < 4; j++) acc[i][j] = mfma16(af[i], bfr[j], acc[i][j]);
  }
  #pragma unroll
  for (int j = 0; j < 4; j++) {
    const int col = n0 + nb + j * 16 + c;
    const float bv_ = bias[col];
    const int h = col >> 6, d = col & 63;
    #pragma unroll
    for (int i = 0; i < 4; i++)
      #pragma unroll
      for (int r = 0; r < 4; r++) {
        const int row = m0 + mb + i * 16 + g * 4 + r;
        const int b = row >> 11, n = row & 2047;
        float v = acc[i][j][r] + bv_;
        if (mode == 0) {
          v *= 0.18033688011112042f;
          dst[((size_t)(b * H_ + h) * NQ_ + n) * DKV_ + d] = f2bf(v);
        } else if (mode == 1) {
          dst[((size_t)(b * H_ + h) * NQ_ + n) * DKV_ + d] = f2bf(v);
        } else {
          dst[((size_t)(b * H_ + h) * DKV_ + d) * NK_ + n] = f2bf(v);
        }
      }
  }
}

// ---------------- attn v9: v7 body + sharing-aware XCD swizzle ------------
// R4 post-mortem: occupancy 38->81% made it WORSE (94.5->105.5us); all pipes
// <25%. With schedule, barrier-drain, and TLP exonerated, the limiter is the
// memory system: ~1.07GB of vmem reads/launch (gp 536MB = 33.5MB unique x16
// heads; K/V 536MB = 8.4MB/b x16 qy-blocks) served almost entirely by L3 at
// ~10-12 TB/s, because data-sharing blocks land on DIFFERENT XCDs under
// round-robin dispatch => zero L2 reuse.
// v9 = v7 body (best lean variant) + block remap so the implied XCD
// (flat%8) groups the 16 h-blocks of one (b,qy): their shared 1MB gp slice
// is fetched into that XCD's L2 once. Per-XCD co-resident set = exactly 4
// groups of 16 (64 blocks at 2/CU). L3-level traffic ~1.07GB -> ~175MB.
__global__ __launch_bounds__(512, 4) void attn_kernel(
    const ushort_t* __restrict__ Qb, const ushort_t* __restrict__ Kb,
    const ushort_t* __restrict__ Vt, const float* __restrict__ gp,
    float* __restrict__ out)
{
  __shared__ ushort_t Ks[2][64 * 72];
  __shared__ ushort_t Vs[2][64 * 72];

  constexpr int NT = NK_ / 64;                    // 32 tiles

  const int tid = threadIdx.x, lane = tid & 63, wid = tid >> 6;  // wid 0..7
  const int c = lane & 15, g = lane >> 4;

  // sharing-aware XCD swizzle: flat%8 ~ XCD (round-robin dispatch).
  // (xcd, i): h = i&15 varies fastest within an XCD => all 16 heads of one
  // (b,qy) co-located; p = xcd + 8*(i>>4) picks the (b,qy) group.
  const int flat = blockIdx.x + (blockIdx.y << 4) + (blockIdx.z << 8); // 0..511
  const int xcd = flat & 7, i = flat >> 3;
  const int h = i & 15;
  const int p = xcd + ((i >> 4) << 3);            // 0..31
  const int b = p >> 4, qy = p & 15;

  const int bh = b * H_ + h;
  const int qw = qy * 128 + wid * 16;

  const ushort_t* Qp = Qb + (size_t)bh * NQ_ * DKV_;
  const ushort_t* Kp = Kb + (size_t)bh * NK_ * DKV_;
  const ushort_t* Vp = Vt + (size_t)bh * DKV_ * NK_;
  const float* gpq = gp + (size_t)b * NQ_ * NK_ + (size_t)(qw + c) * NK_;

  // cooperative staging: 512 threads cover 64x64, 1 chunk each for K and V
  const int srow = tid >> 3;                      // 0..63
  const int u    = tid & 7;                       // source 8-chunk index
  const int scol = u * 8;
  // sigma slots for V: source k-run [8u,8u+4) -> so_lo, [8u+4,8u+8) -> so_hi
  const int so_lo = 32 * (u >> 2) + 8 * ((2 * u) & 3) + 4 * ((u >> 1) & 1);
  const int so_hi = 32 * (u >> 2) + 8 * ((2 * u + 1) & 3) + 4 * ((u >> 1) & 1);

  // Q fragments resident (pre-scaled by log2(e)/8)
  short8 qf[2];
  #pragma unroll
  for (int kc = 0; kc < 2; kc++)
    qf[kc] = *(const short8*)&Qp[(qw + c) * DKV_ + kc * 32 + g * 8];

  // ---- prologue: stage tile 0 direct; prefetch tile 1 + gp(0) into regs --
  *(short8*)&Ks[0][srow * 72 + scol] = *(const short8*)&Kp[(size_t)srow * DKV_ + scol];
  {
    short8 v8 = *(const short8*)&Vp[(size_t)srow * NK_ + scol];
    short4v vl, vh;
    #pragma unroll
    for (int e = 0; e < 4; e++) { vl[e] = v8[e]; vh[e] = v8[4 + e]; }
    *(short4v*)&Vs[0][srow * 72 + so_lo] = vl;
    *(short4v*)&Vs[0][srow * 72 + so_hi] = vh;
  }
  short8 kA = *(const short8*)&Kp[(size_t)(64 + srow) * DKV_ + scol];
  short8 vA = *(const short8*)&Vp[(size_t)srow * NK_ + 64 + scol];
  short8 kB = {}, vB = {};
  floatx4 gpA[4], gpB[4];
  #pragma unroll
  for (int jk = 0; jk < 4; jk++)
    gpA[jk] = *(const floatx4*)&gpq[jk * 16 + g * 4];
  __syncthreads();   // one-time full drain at start: negligible

  floatx4 o[4];
  float l = 0.f;
  #pragma unroll
  for (int jd = 0; jd < 4; jd++) o[jd] = floatx4{0.f, 0.f, 0.f, 0.f};

  // body: compute tile T from LDS[CUR] gated by GPC; issue loads for T+2
  // into (KB,VB); issue gp(T+1) into GPN; commit (KA,VA)=tile T+1 late.
#define ATTN_BODY(T, CUR, GPC, GPN, KA, VA, KB, VB)                          \
  {                                                                          \
    const int t_ = (T);                                                      \
    /* issue tile t+2 staging loads FIRST (oldest in vmem queue, so the   */ \
    /* commit's auto vmcnt wait leaves the younger gp loads in flight)    */ \
    if (t_ + 2 < NT) {                                                       \
      const int k2 = (t_ + 2) * 64;                                          \
      KB = *(const short8*)&Kp[(size_t)(k2 + srow) * DKV_ + scol];           \
      VB = *(const short8*)&Vp[(size_t)srow * NK_ + k2 + scol];              \
    }                                                                        \
    /* issue gp(t+1) (consumed next iter) */                                 \
    if (t_ + 1 < NT) {                                                       \
      const int k1 = (t_ + 1) * 64;                                          \
      _Pragma("unroll")                                                      \
      for (int jk = 0; jk < 4; jk++)                                         \
        GPN[jk] = *(const floatx4*)&gpq[k1 + jk * 16 + g * 4];               \
    }                                                                        \
    /* S = K Q^T (log2 domain): lane holds q=c, k=jk*16+4g+r */              \
    floatx4 s_[4];                                                           \
    _Pragma("unroll")                                                        \
    for (int jk = 0; jk < 4; jk++) {                                         \
      s_[jk] = floatx4{0.f, 0.f, 0.f, 0.f};                                  \
      _Pragma("unroll")                                                      \
      for (int kc = 0; kc < 2; kc++) {                                       \
        short8 kf = *(const short8*)&Ks[CUR][(jk * 16 + c) * 72 + kc * 32 + g * 8]; \
        s_[jk] = mfma16(kf, qf[kc], s_[jk]);                                 \
      }                                                                      \
    }                                                                        \
    /* p = exp2(s); l += p; gate by gp; pack A-frags in-register */          \
    uintx4 afw_[2];                                                          \
    _Pragma("unroll")                                                        \
    for (int jk = 0; jk < 4; jk++) {                                         \
      const float p0 = fexp2(s_[jk][0]);                                     \
      const float p1 = fexp2(s_[jk][1]);                                     \
      const float p2 = fexp2(s_[jk][2]);                                     \
      const float p3 = fexp2(s_[jk][3]);                                     \
      l += (p0 + p1) + (p2 + p3);                                            \
      const unsigned int w0 = cvt_pk_bf16(p0 * GPC[jk][0], p1 * GPC[jk][1]); \
      const unsigned int w1 = cvt_pk_bf16(p2 * GPC[jk][2], p3 * GPC[jk][3]); \
      afw_[jk >> 1][2 * (jk & 1) + 0] = w0;                                  \
      afw_[jk >> 1][2 * (jk & 1) + 1] = w1;                                  \
    }                                                                        \
    /* PV: A = in-register P frags, B = sigma-permuted V from LDS */         \
    _Pragma("unroll")                                                        \
    for (int kc = 0; kc < 2; kc++) {                                         \
      const short8 af_ = __builtin_bit_cast(short8, afw_[kc]);               \
      _Pragma("unroll")                                                      \
      for (int jd = 0; jd < 4; jd++) {                                       \
        short8 vf = *(const short8*)&Vs[CUR][(jd * 16 + c) * 72 + kc * 32 + g * 8]; \
        o[jd] = mfma16(af_, vf, o[jd]);                                      \
      }                                                                      \
    }                                                                        \
    /* commit tile t+1 (issued last iter): auto-counted vmcnt lands HERE */  \
    if (t_ + 1 < NT) {                                                       \
      *(short8*)&Ks[(CUR) ^ 1][srow * 72 + scol] = KA;                       \
      short4v vl_, vh_;                                                      \
      _Pragma("unroll")                                                      \
      for (int e = 0; e < 4; e++) { vl_[e] = VA[e]; vh_[e] = VA[4 + e]; }    \
      *(short4v*)&Vs[(CUR) ^ 1][srow * 72 + so_lo] = vl_;                    \
      *(short4v*)&Vs[(CUR) ^ 1][srow * 72 + so_hi] = vh_;                    \
    }                                                                        \
    block_sync_lds();                                                        \
  }

  for (int tt = 0; tt < NT; tt += 2) {
    ATTN_BODY(tt,     0, gpA, gpB, kA, vA, kB, vB)
    ATTN_BODY(tt + 1, 1, gpB, gpA, kB, vB, kA, vA)
  }
#undef ATTN_BODY

  // l lives per q=c; reduce across the 4 g-groups, then redistribute to the
  // output layout's q = 4g + r via shfl (once per kernel).
  float lf = l;
  lf += __shfl_xor(lf, 16);
  lf += __shfl_xor(lf, 32);
  const float inv = frcp(lf);
  float invr[4];
  #pragma unroll
  for (int r = 0; r < 4; r++) invr[r] = __shfl(inv, g * 4 + r);

  #pragma unroll
  for (int jd = 0; jd < 4; jd++)
    #pragma unroll
    for (int r = 0; r < 4; r++) {
      const int row = qw + g * 4 + r;
      out[(size_t)(b * NQ_ + row) * 1024 + h * 64 + jd * 16 + c] =
          o[jd][r] * invr[r];
    }
}

extern "C" void kernel_launch(void* const* d_in, const int* in_sizes, int n_in,
                              void* d_out, int out_size, void* d_ws, size_t ws_size,
                              hipStream_t stream) {
  const float* queries = (const float*)d_in[0];
  const float* keys    = (const float*)d_in[1];
  const float* values  = (const float*)d_in[2];
  const float* gp      = (const float*)d_in[3];
  // d_in[4] attention_mask: intentionally unused (reference discards it)
  const float* Wq = (const float*)d_in[5];
  const float* bq = (const float*)d_in[6];
  const float* Wk = (const float*)d_in[7];
  const float* bk = (const float*)d_in[8];
  const float* Wv = (const float*)d_in[9];
  const float* bv = (const float*)d_in[10];

  const size_t SZ_QKV = (size_t)3 * B_ * H_ * NQ_ * DKV_;  // shorts
  const size_t SZ_X   = (size_t)3 * 4096 * 1024;
  const size_t SZ_W   = (size_t)3 * 1024 * 1024;
  const size_t NEED   = (SZ_QKV + SZ_X + SZ_W) * sizeof(ushort_t);

  ushort_t* Qb = (ushort_t*)d_ws;                       // [B,H,NQ,64] bf16, pre-scaled
  ushort_t* Kb = Qb + (size_t)B_ * H_ * NQ_ * DKV_;     // [B,H,NK,64] bf16
  ushort_t* Vt = Kb + (size_t)B_ * H_ * NK_ * DKV_;     // [B,H,64,NK] bf16
  float* out = (float*)d_out;

  if (ws_size >= NEED) {
    ushort_t* Xbf = Qb + SZ_QKV;
    ushort_t* Wt  = Xbf + SZ_X;
    cast_x_kernel<<<dim3(512, 3), 256, 0, stream>>>(queries, keys, values, Xbf);
    cast_wt_kernel<<<dim3(32, 32, 3), 256, 0, stream>>>(Wq, Wk, Wv, Wt);
    proj_kernel2<<<dim3(8, 32, 3), 256, 0, stream>>>(
        Xbf, Wt, bq, bk, bv, Qb, Kb, Vt);
  } else {
    proj_kernel_fb<<<dim3(8, 32, 3), 256, 0, stream>>>(
        queries, keys, values, Wq, Wk, Wv, bq, bk, bv, Qb, Kb, Vt);
  }
  attn_kernel<<<dim3(H_, NQ_ / 128, B_), 512, 0, stream>>>(Qb, Kb, Vt, gp, out);
}